// Round 1
// baseline (262.554 us; speedup 1.0000x reference)
//
#include <hip/hip_runtime.h>

#define NQ 20
#define NS (1 << NQ)

// broadcast lane0's value to all lanes -> lets compiler keep it in an SGPR
__device__ __forceinline__ float bcast_first(float x) {
    return __int_as_float(__builtin_amdgcn_readfirstlane(__float_as_int(x)));
}

// RX butterfly, symmetric form: new = C*mine + SV*(partner.im, -partner.re)
// Pass 1: qubits 19..9 == state-index bits 0..10. One wave owns 2048 contiguous
// elements: reg bits {0,1,8,9,10}, lane bits {2..7}. Reads real phi, writes
// complex float2 into d_out (which doubles as the intermediate buffer).
__global__ __launch_bounds__(256) void rx_pass1(
        const float* __restrict__ phi, const float* __restrict__ thetas,
        float2* __restrict__ out) {
    const int lane = threadIdx.x & 63;
    const int W = (blockIdx.x << 2) + (threadIdx.x >> 6);   // wave id [0,8192)
    const int b = W >> 9;                                    // batch
    const int base = (W & 511) << 11;                        // element base in state
    const float* ph = phi + ((size_t)b << NQ) + base;
    float2* op = out + ((size_t)b << NQ) + base;

    // bit beta (0..10) -> qubit 19-beta
    float c[11], sv[11];
#pragma unroll
    for (int beta = 0; beta < 11; ++beta) {
        float th = 0.5f * thetas[b * NQ + (NQ - 1 - beta)];
        c[beta]  = bcast_first(cosf(th));
        sv[beta] = bcast_first(sinf(th));
    }

    // local idx = k4*256 + lane*4 + j ; reg r = k4*4 + j
    float2 v[32];
#pragma unroll
    for (int k4 = 0; k4 < 8; ++k4) {
        float4 t = *(const float4*)(ph + (k4 << 8) + (lane << 2));
        v[k4 * 4 + 0] = make_float2(t.x, 0.f);
        v[k4 * 4 + 1] = make_float2(t.y, 0.f);
        v[k4 * 4 + 2] = make_float2(t.z, 0.f);
        v[k4 * 4 + 3] = make_float2(t.w, 0.f);
    }

    // register-owned bits: bit0 -> reg mask1, bit1 -> mask2, bits 8,9,10 -> mask 4,8,16
    const int regbit[5]  = {0, 1, 8, 9, 10};
    const int regmask[5] = {1, 2, 4, 8, 16};
#pragma unroll
    for (int t = 0; t < 5; ++t) {
        const float C = c[regbit[t]], SV = sv[regbit[t]];
        const int m = regmask[t];
#pragma unroll
        for (int r = 0; r < 32; ++r) {
            if (!(r & m)) {
                const int r1 = r | m;
                float2 a = v[r], bb = v[r1];
                v[r]  = make_float2(C * a.x + SV * bb.y, C * a.y - SV * bb.x);
                v[r1] = make_float2(C * bb.x + SV * a.y, C * bb.y - SV * a.x);
            }
        }
    }

    // lane-owned bits 2..7: lanemask 1<<(bit-2)
#pragma unroll
    for (int t = 0; t < 6; ++t) {
        const float C = c[2 + t], SV = sv[2 + t];
        const int m = 1 << t;
#pragma unroll
        for (int r = 0; r < 32; ++r) {
            float pr = __shfl_xor(v[r].x, m, 64);
            float pi = __shfl_xor(v[r].y, m, 64);
            v[r] = make_float2(C * v[r].x + SV * pi, C * v[r].y - SV * pr);
        }
    }

    // store: 2 float4 per k4 (covers 4 consecutive complex)
#pragma unroll
    for (int k4 = 0; k4 < 8; ++k4) {
        float2* dst = op + (k4 << 8) + (lane << 2);
        *(float4*)(dst)     = make_float4(v[k4*4+0].x, v[k4*4+0].y, v[k4*4+1].x, v[k4*4+1].y);
        *(float4*)(dst + 2) = make_float4(v[k4*4+2].x, v[k4*4+2].y, v[k4*4+3].x, v[k4*4+3].y);
    }
}

// Pass 2: qubits 8..0 == bits 11..19. One wave owns all 512 high combinations
// for 4 contiguous low indices: reg bits {11..15}, lane bits {16..19}.
// In-place on d_out; each wave's element set is closed under its bits -> no races.
__global__ __launch_bounds__(256) void rx_pass2(
        const float* __restrict__ thetas, float2* __restrict__ out) {
    const int lane = threadIdx.x & 63;
    const int W = (blockIdx.x << 2) + (threadIdx.x >> 6);   // wave id [0,8192)
    const int b = W >> 9;
    const int low = ((W & 511) << 2) + (lane & 3);
    const int hl = lane >> 2;                                // bits 16..19
    float2* p = out + ((size_t)b << NQ);

    // local t (0..8): bit 11+t -> qubit 8-t
    float c[9], sv[9];
#pragma unroll
    for (int t = 0; t < 9; ++t) {
        float th = 0.5f * thetas[b * NQ + (8 - t)];
        c[t]  = bcast_first(cosf(th));
        sv[t] = bcast_first(sinf(th));
    }

    float2 v[32];
#pragma unroll
    for (int k = 0; k < 32; ++k)
        v[k] = p[(((hl << 5) | k) << 11) + low];

    // reg bits 11..15 -> reg mask 1<<t
#pragma unroll
    for (int t = 0; t < 5; ++t) {
        const float C = c[t], SV = sv[t];
        const int m = 1 << t;
#pragma unroll
        for (int r = 0; r < 32; ++r) {
            if (!(r & m)) {
                const int r1 = r | m;
                float2 a = v[r], bb = v[r1];
                v[r]  = make_float2(C * a.x + SV * bb.y, C * a.y - SV * bb.x);
                v[r1] = make_float2(C * bb.x + SV * a.y, C * bb.y - SV * a.x);
            }
        }
    }

    // lane bits 16..19 -> lanemask 4,8,16,32
#pragma unroll
    for (int t = 5; t < 9; ++t) {
        const float C = c[t], SV = sv[t];
        const int m = 4 << (t - 5);
#pragma unroll
        for (int r = 0; r < 32; ++r) {
            float pr = __shfl_xor(v[r].x, m, 64);
            float pi = __shfl_xor(v[r].y, m, 64);
            v[r] = make_float2(C * v[r].x + SV * pi, C * v[r].y - SV * pr);
        }
    }

#pragma unroll
    for (int k = 0; k < 32; ++k)
        p[(((hl << 5) | k) << 11) + low] = v[k];
}

extern "C" void kernel_launch(void* const* d_in, const int* in_sizes, int n_in,
                              void* d_out, int out_size, void* d_ws, size_t ws_size,
                              hipStream_t stream) {
    const float* phi    = (const float*)d_in[0];
    const float* thetas = (const float*)d_in[1];
    float2* out = (float2*)d_out;
    // 16 batches * 2^20 elements / 2048 per wave = 8192 waves = 2048 blocks of 4 waves
    rx_pass1<<<2048, 256, 0, stream>>>(phi, thetas, out);
    rx_pass2<<<2048, 256, 0, stream>>>(thetas, out);
}

// Round 2
// 245.049 us; speedup vs baseline: 1.0714x; 1.0714x over previous
//
#include <hip/hip_runtime.h>

#define NQ 20

__device__ __forceinline__ float bcast_first(float x) {
    return __int_as_float(__builtin_amdgcn_readfirstlane(__float_as_int(x)));
}

// RX butterfly, symmetric form: new = C*mine + SV*(partner.im, -partner.re)
__device__ __forceinline__ void bfly(float C, float SV, float2& a, float2& b) {
    float2 na = make_float2(C * a.x + SV * b.y, C * a.y - SV * b.x);
    float2 nb = make_float2(C * b.x + SV * a.y, C * b.y - SV * a.x);
    a = na; b = nb;
}

// swizzled LDS index for pass1: XOR bits 2..4 by bits 7..9 of the local index
__device__ __forceinline__ int swz1(int l) { return l ^ (((l >> 7) & 7) << 2); }

// Pass 1: state-index bits 0..10 (qubits 19..9). One wave (=one 64-thread block)
// owns 2048 contiguous complex. Three register assignments, two in-wave LDS
// exchanges, zero cross-lane shuffles. Reads real phi, writes complex to out.
__global__ __launch_bounds__(64) void rx_pass1(
        const float* __restrict__ phi, const float* __restrict__ thetas,
        float2* __restrict__ out) {
    __shared__ float2 lds[2048];                    // 16 KiB
    const int lane = threadIdx.x;
    const int W = blockIdx.x;                       // [0, 8192)
    const int b = W >> 9;
    const int base = (W & 511) << 11;
    const float* ph = phi + ((size_t)b << NQ) + base;
    float2* op = out + ((size_t)b << NQ) + base;

    // bit beta (0..10) -> qubit 19-beta
    float c[11], sv[11];
#pragma unroll
    for (int beta = 0; beta < 11; ++beta) {
        float th = 0.5f * thetas[b * NQ + (NQ - 1 - beta)];
        c[beta]  = bcast_first(cosf(th));
        sv[beta] = bcast_first(sinf(th));
    }

    // Assignment 1: low = k4*256 + lane*4 + j ; reg bits {0,1,8,9,10}
    float2 v[32];
#pragma unroll
    for (int k4 = 0; k4 < 8; ++k4) {
        float4 t = *(const float4*)(ph + (k4 << 8) + (lane << 2));
        v[k4 * 4 + 0] = make_float2(t.x, 0.f);
        v[k4 * 4 + 1] = make_float2(t.y, 0.f);
        v[k4 * 4 + 2] = make_float2(t.z, 0.f);
        v[k4 * 4 + 3] = make_float2(t.w, 0.f);
    }

    const int regbit1[5]  = {0, 1, 8, 9, 10};
    const int regmask1[5] = {1, 2, 4, 8, 16};
#pragma unroll
    for (int t = 0; t < 5; ++t) {
        const float C = c[regbit1[t]], SV = sv[regbit1[t]];
        const int m = regmask1[t];
#pragma unroll
        for (int r = 0; r < 32; ++r)
            if (!(r & m)) bfly(C, SV, v[r], v[r | m]);
    }

    // Exchange 1: write assignment-1 layout to swizzled LDS (b128, conflict-floor)
#pragma unroll
    for (int k4 = 0; k4 < 8; ++k4) {
        int low0 = (k4 << 8) + (lane << 2);
        int s0 = swz1(low0);                         // preserves bits 0..1
        *(float4*)&lds[s0]     = make_float4(v[k4*4+0].x, v[k4*4+0].y, v[k4*4+1].x, v[k4*4+1].y);
        *(float4*)&lds[s0 + 2] = make_float4(v[k4*4+2].x, v[k4*4+2].y, v[k4*4+3].x, v[k4*4+3].y);
    }
    __syncthreads();

    // Assignment 2: low = g*128 + r*4 + lam ; reg bits {2..6}; g=lane>>2 (bits 7..10)
    {
        const int g = lane >> 2, lam = lane & 3;
        float2 w2[32];
#pragma unroll
        for (int r = 0; r < 32; ++r) {
            int l = (g << 7) | (r << 2) | lam;
            w2[r] = lds[swz1(l)];
        }
#pragma unroll
        for (int t = 0; t < 5; ++t) {
            const float C = c[2 + t], SV = sv[2 + t];
            const int m = 1 << t;
#pragma unroll
            for (int r = 0; r < 32; ++r)
                if (!(r & m)) bfly(C, SV, w2[r], w2[r | m]);
        }
        // Exchange 2: write back (same addresses -> same bank floor)
#pragma unroll
        for (int r = 0; r < 32; ++r) {
            int l = (g << 7) | (r << 2) | lam;
            lds[swz1(l)] = w2[r];
        }
    }
    __syncthreads();

    // Assignment 3: thread owns complex pairs {l0, l0+1}; l0 = lane*2 + (m -> bits 7..10).
    // Reg stage for bit 7, then DENSE float4 stores (lanes stride 16B -> 1KB/instr).
    float4 u[16];
#pragma unroll
    for (int m = 0; m < 16; ++m) {
        int l0 = (lane << 1) | ((m & 1) << 7) | (((m >> 1) & 1) << 8)
               | (((m >> 2) & 1) << 9) | (((m >> 3) & 1) << 10);
        u[m] = *(float4*)&lds[swz1(l0)];
    }
    {
        const float C = c[7], SV = sv[7];
#pragma unroll
        for (int m = 0; m < 16; m += 2) {
            float4 A = u[m], B = u[m + 1];
            u[m]     = make_float4(C*A.x + SV*B.y, C*A.y - SV*B.x, C*A.z + SV*B.w, C*A.w - SV*B.z);
            u[m + 1] = make_float4(C*B.x + SV*A.y, C*B.y - SV*A.x, C*B.z + SV*A.w, C*B.w - SV*A.z);
        }
    }
#pragma unroll
    for (int m = 0; m < 16; ++m) {
        int l0 = (lane << 1) | ((m & 1) << 7) | (((m >> 1) & 1) << 8)
               | (((m >> 2) & 1) << 9) | (((m >> 3) & 1) << 10);
        *(float4*)(op + l0) = u[m];
    }
}

// Pass 2: bits 11..19 (qubits 8..0). LDS-staged tile: 512 h-combos x 16 low
// offsets = 64 KiB. Block = 512 threads. Global access 128B segments both ways.
// h-bit i <-> qubit 8-i. In-LDS swizzle: stored_l = l ^ ((h&7)<<1).
__global__ __launch_bounds__(512) void rx_pass2(
        const float* __restrict__ thetas, float2* __restrict__ out) {
    __shared__ float2 buf[8192];                    // 64 KiB
    const int tid = threadIdx.x;
    const int lane = tid & 63;
    const int w = tid >> 6;                         // 0..7
    const int b = blockIdx.x >> 7;
    const int lb = blockIdx.x & 127;
    float2* p = out + ((size_t)b << NQ) + (lb << 4);

    float c[9], sv[9];
#pragma unroll
    for (int i = 0; i < 9; ++i) {
        float th = 0.5f * thetas[b * NQ + (8 - i)];
        c[i]  = bcast_first(cosf(th));
        sv[i] = bcast_first(sinf(th));
    }

    // Stage A: global -> LDS. f = i*512 + tid: h = f>>3, j = f&7 (float4 in h's row)
#pragma unroll
    for (int i = 0; i < 8; ++i) {
        int f = (i << 9) | tid;
        int h = f >> 3, j = f & 7;
        float4 t = *(const float4*)(p + h * 2048 + (j << 1));
        *(float4*)&buf[(h << 4) | (((j << 1) ^ ((h & 7) << 1)))] = t;
    }
    __syncthreads();

    // Stage B: butterfly layout. l = (w<<1)|(lane>>5); h = (r<<5)|(lane&31)
    const int l = (w << 1) | (lane >> 5);
    const int g5 = lane & 31;
    float2 v[16];
#pragma unroll
    for (int r = 0; r < 16; ++r) {
        int h = (r << 5) | g5;
        v[r] = buf[(h << 4) | (l ^ ((h & 7) << 1))];
    }

    // h bits 0..4 live on lane bits 0..4 -> shuffle stages (masks 1..16)
#pragma unroll
    for (int t = 0; t < 5; ++t) {
        const float C = c[t], SV = sv[t];
        const int m = 1 << t;
#pragma unroll
        for (int r = 0; r < 16; ++r) {
            float pr = __shfl_xor(v[r].x, m, 64);
            float pi = __shfl_xor(v[r].y, m, 64);
            v[r] = make_float2(C * v[r].x + SV * pi, C * v[r].y - SV * pr);
        }
    }
    // h bits 5..8 on regs (masks 1,2,4,8)
#pragma unroll
    for (int t = 0; t < 4; ++t) {
        const float C = c[5 + t], SV = sv[5 + t];
        const int m = 1 << t;
#pragma unroll
        for (int r = 0; r < 16; ++r)
            if (!(r & m)) bfly(C, SV, v[r], v[r | m]);
    }

    // Stage C: write back (same slots this thread read -> no extra barrier needed before)
#pragma unroll
    for (int r = 0; r < 16; ++r) {
        int h = (r << 5) | g5;
        buf[(h << 4) | (l ^ ((h & 7) << 1))] = v[r];
    }
    __syncthreads();

    // Stage D: LDS -> global, same mapping as A
#pragma unroll
    for (int i = 0; i < 8; ++i) {
        int f = (i << 9) | tid;
        int h = f >> 3, j = f & 7;
        float4 t = *(float4*)&buf[(h << 4) | (((j << 1) ^ ((h & 7) << 1)))];
        *(float4*)(p + h * 2048 + (j << 1)) = t;
    }
}

extern "C" void kernel_launch(void* const* d_in, const int* in_sizes, int n_in,
                              void* d_out, int out_size, void* d_ws, size_t ws_size,
                              hipStream_t stream) {
    const float* phi    = (const float*)d_in[0];
    const float* thetas = (const float*)d_in[1];
    float2* out = (float2*)d_out;
    rx_pass1<<<8192, 64, 0, stream>>>(phi, thetas, out);
    rx_pass2<<<2048, 512, 0, stream>>>(thetas, out);
}

// Round 3
// 239.685 us; speedup vs baseline: 1.0954x; 1.0224x over previous
//
#include <hip/hip_runtime.h>

#define NQ 20

__device__ __forceinline__ float bcast_first(float x) {
    return __int_as_float(__builtin_amdgcn_readfirstlane(__float_as_int(x)));
}

// RX butterfly, symmetric form: new = C*mine + SV*(partner.im, -partner.re)
__device__ __forceinline__ void bfly(float C, float SV, float2& a, float2& b) {
    float2 na = make_float2(C * a.x + SV * b.y, C * a.y - SV * b.x);
    float2 nb = make_float2(C * b.x + SV * a.y, C * b.y - SV * a.x);
    a = na; b = nb;
}

// vectorized over two complex packed in float4 (same butterfly both halves)
__device__ __forceinline__ void bfly4(float C, float SV, float4& a, float4& b) {
    float4 na = make_float4(C*a.x + SV*b.y, C*a.y - SV*b.x, C*a.z + SV*b.w, C*a.w - SV*b.z);
    float4 nb = make_float4(C*b.x + SV*a.y, C*b.y - SV*a.x, C*b.z + SV*a.w, C*b.w - SV*a.z);
    a = na; b = nb;
}

// swizzled LDS index for pass1: XOR bits 2..4 by bits 7..9 of the local index
__device__ __forceinline__ int swz1(int l) { return l ^ (((l >> 7) & 7) << 2); }

// Pass 1: state-index bits 0..10 (qubits 19..9). One wave (=one 64-thread block)
// owns 2048 contiguous complex. Three register assignments, two in-wave LDS
// exchanges, zero cross-lane shuffles. Reads real phi, writes complex to out.
// (unchanged from R2 — est ~memory-bound; LDS budget ~11us total, under 30us mem)
__global__ __launch_bounds__(64) void rx_pass1(
        const float* __restrict__ phi, const float* __restrict__ thetas,
        float2* __restrict__ out) {
    __shared__ float2 lds[2048];                    // 16 KiB
    const int lane = threadIdx.x;
    const int W = blockIdx.x;                       // [0, 8192)
    const int b = W >> 9;
    const int base = (W & 511) << 11;
    const float* ph = phi + ((size_t)b << NQ) + base;
    float2* op = out + ((size_t)b << NQ) + base;

    float c[11], sv[11];
#pragma unroll
    for (int beta = 0; beta < 11; ++beta) {
        float th = 0.5f * thetas[b * NQ + (NQ - 1 - beta)];
        c[beta]  = bcast_first(cosf(th));
        sv[beta] = bcast_first(sinf(th));
    }

    float2 v[32];
#pragma unroll
    for (int k4 = 0; k4 < 8; ++k4) {
        float4 t = *(const float4*)(ph + (k4 << 8) + (lane << 2));
        v[k4 * 4 + 0] = make_float2(t.x, 0.f);
        v[k4 * 4 + 1] = make_float2(t.y, 0.f);
        v[k4 * 4 + 2] = make_float2(t.z, 0.f);
        v[k4 * 4 + 3] = make_float2(t.w, 0.f);
    }

    const int regbit1[5]  = {0, 1, 8, 9, 10};
    const int regmask1[5] = {1, 2, 4, 8, 16};
#pragma unroll
    for (int t = 0; t < 5; ++t) {
        const float C = c[regbit1[t]], SV = sv[regbit1[t]];
        const int m = regmask1[t];
#pragma unroll
        for (int r = 0; r < 32; ++r)
            if (!(r & m)) bfly(C, SV, v[r], v[r | m]);
    }

#pragma unroll
    for (int k4 = 0; k4 < 8; ++k4) {
        int low0 = (k4 << 8) + (lane << 2);
        int s0 = swz1(low0);
        *(float4*)&lds[s0]     = make_float4(v[k4*4+0].x, v[k4*4+0].y, v[k4*4+1].x, v[k4*4+1].y);
        *(float4*)&lds[s0 + 2] = make_float4(v[k4*4+2].x, v[k4*4+2].y, v[k4*4+3].x, v[k4*4+3].y);
    }
    __syncthreads();

    {
        const int g = lane >> 2, lam = lane & 3;
        float2 w2[32];
#pragma unroll
        for (int r = 0; r < 32; ++r) {
            int l = (g << 7) | (r << 2) | lam;
            w2[r] = lds[swz1(l)];
        }
#pragma unroll
        for (int t = 0; t < 5; ++t) {
            const float C = c[2 + t], SV = sv[2 + t];
            const int m = 1 << t;
#pragma unroll
            for (int r = 0; r < 32; ++r)
                if (!(r & m)) bfly(C, SV, w2[r], w2[r | m]);
        }
#pragma unroll
        for (int r = 0; r < 32; ++r) {
            int l = (g << 7) | (r << 2) | lam;
            lds[swz1(l)] = w2[r];
        }
    }
    __syncthreads();

    float4 u[16];
#pragma unroll
    for (int m = 0; m < 16; ++m) {
        int l0 = (lane << 1) | ((m & 1) << 7) | (((m >> 1) & 1) << 8)
               | (((m >> 2) & 1) << 9) | (((m >> 3) & 1) << 10);
        u[m] = *(float4*)&lds[swz1(l0)];
    }
    {
        const float C = c[7], SV = sv[7];
#pragma unroll
        for (int m = 0; m < 16; m += 2) {
            float4 A = u[m], B = u[m + 1];
            u[m]     = make_float4(C*A.x + SV*B.y, C*A.y - SV*B.x, C*A.z + SV*B.w, C*A.w - SV*B.z);
            u[m + 1] = make_float4(C*B.x + SV*A.y, C*B.y - SV*A.x, C*B.z + SV*A.w, C*B.w - SV*A.z);
        }
    }
#pragma unroll
    for (int m = 0; m < 16; ++m) {
        int l0 = (lane << 1) | ((m & 1) << 7) | (((m >> 1) & 1) << 8)
               | (((m >> 2) & 1) << 9) | (((m >> 3) & 1) << 10);
        *(float4*)(op + l0) = u[m];
    }
}

// ---------------------------------------------------------------------------
// Pass 2 (rewritten, shuffle-free): bits 11..19 (qubits 8..0).
// Block = 256 threads, tile = 512 h-combos x 16 low offsets = 64 KiB LDS.
// LDS layout: row h = 16 complex (128B); pair-slot q swizzled by h bits.
// Stage A: coalesced global->LDS.  B2: h-bits 5..8 as register butterflies
// vectorized over low-pairs (b128 LDS).  Exchange.  B1: h-bits 0..4 register
// butterflies, stores straight to global (16 lanes = 128B contiguous).
// ---------------------------------------------------------------------------
__device__ __forceinline__ int ppos(int h, int q) {
    return (h << 4) + (((q ^ (h & 7) ^ ((h >> 5) & 7)) & 7) << 1);
}

__global__ __launch_bounds__(256) void rx_pass2(
        const float* __restrict__ thetas, float2* __restrict__ out) {
    __shared__ float2 buf[8192];                    // 64 KiB
    const int tid = threadIdx.x;
    const int b = blockIdx.x >> 7;
    const int lb = blockIdx.x & 127;
    float2* p = out + ((size_t)b << NQ) + (lb << 4);

    // h-bit i <-> qubit 8-i
    float c[9], sv[9];
#pragma unroll
    for (int i = 0; i < 9; ++i) {
        float th = 0.5f * thetas[b * NQ + (8 - i)];
        c[i]  = bcast_first(cosf(th));
        sv[i] = bcast_first(sinf(th));
    }

    // Stage A: global -> LDS, 16 float4/thread, 128B-chunk coalesced
#pragma unroll
    for (int i = 0; i < 16; ++i) {
        int f = (i << 8) | tid;                     // [0, 4096)
        int h = f >> 3, j = f & 7;
        float4 t = *(const float4*)(p + h * 2048 + (j << 1));
        *(float4*)&buf[ppos(h, j)] = t;
    }
    __syncthreads();

    // Stage B2: h bits 5..8 (qubits 3..0), regs m in [0,16), vectorized low-pair
    {
        const int hl = tid & 31;                    // h bits 0..4
        const int j  = tid >> 5;                    // low pair [0,8)
        float4 w[16];
#pragma unroll
        for (int m = 0; m < 16; ++m)
            w[m] = *(float4*)&buf[ppos((m << 5) | hl, j)];
#pragma unroll
        for (int t = 0; t < 4; ++t) {
            const float C = c[5 + t], SV = sv[5 + t];
            const int msk = 1 << t;
#pragma unroll
            for (int m = 0; m < 16; ++m)
                if (!(m & msk)) bfly4(C, SV, w[m], w[m | msk]);
        }
#pragma unroll
        for (int m = 0; m < 16; ++m)
            *(float4*)&buf[ppos((m << 5) | hl, j)] = w[m];
    }
    __syncthreads();

    // Stage B1: h bits 0..4 (qubits 8..4), regs r in [0,32), direct global store
    {
        const int hh = tid >> 4;                    // h bits 5..8
        const int ll = tid & 15;                    // low offset
        float2 v[32];
#pragma unroll
        for (int r = 0; r < 32; ++r) {
            int h = (hh << 5) | r;
            v[r] = buf[ppos(h, ll >> 1) + (ll & 1)];
        }
#pragma unroll
        for (int t = 0; t < 5; ++t) {
            const float C = c[t], SV = sv[t];
            const int msk = 1 << t;
#pragma unroll
            for (int r = 0; r < 32; ++r)
                if (!(r & msk)) bfly(C, SV, v[r], v[r | msk]);
        }
#pragma unroll
        for (int r = 0; r < 32; ++r) {
            int h = (hh << 5) | r;
            p[h * 2048 + ll] = v[r];
        }
    }
}

extern "C" void kernel_launch(void* const* d_in, const int* in_sizes, int n_in,
                              void* d_out, int out_size, void* d_ws, size_t ws_size,
                              hipStream_t stream) {
    const float* phi    = (const float*)d_in[0];
    const float* thetas = (const float*)d_in[1];
    float2* out = (float2*)d_out;
    rx_pass1<<<8192, 64, 0, stream>>>(phi, thetas, out);
    rx_pass2<<<2048, 256, 0, stream>>>(thetas, out);
}